// Round 6
// baseline (267.325 us; speedup 1.0000x reference)
//
#include <hip/hip_runtime.h>
#include <math.h>

typedef unsigned short ushort_t;
typedef __attribute__((ext_vector_type(8))) short bf16x8;   // MFMA A/B frag (4 VGPR)
typedef __attribute__((ext_vector_type(4))) float f32x4;    // MFMA C/D frag

// r5 post-mortem: top-5 = fillBufferAligned (44us, harness workspace poison,
// uncontrollable) + edge_attn<64> (43us, VALU 71%, HBM 15% -> VALU/latency
// bound, one node/wave, 4 dims/lane, deg-16 node = only ~4 rounds).
// r6: edge_attn goes 8 dims/lane (uint4): LPE 16->8 (D=64), 8->4 (D=32);
// 2x edges per wave-instruction, half the rounds/node, 16B/lane loads.
#define NBLK  128         // histogram blocks (each owns E/NBLK edges)
#define MAXNH 25024       // LDS uints for packed 2x16b counters (n <= 50048)

// ---------------------------------------------------------------------------
// DPP-based add: x += x[lane ^ pattern], pure VALU.
// ---------------------------------------------------------------------------
template<int CTRL>
__device__ __forceinline__ float dpp_addf(float x)
{
    int y = __builtin_amdgcn_update_dpp(0, __float_as_int(x), CTRL, 0xf, 0xf, true);
    return x + __int_as_float(y);
}

template<int LPE>
__device__ __forceinline__ float group_reduce(float p)
{
    p = dpp_addf<0xB1>(p);                           // xor 1
    p = dpp_addf<0x4E>(p);                           // xor 2
    if constexpr (LPE >= 8)  p = dpp_addf<0x141>(p); // xor 7 (row_half_mirror)
    if constexpr (LPE >= 16) p = dpp_addf<0x140>(p); // xor 15 (row_mirror)
    return p;
}

__device__ __forceinline__ ushort_t f2bf(float f)
{
    unsigned u = __float_as_uint(f);
    return (ushort_t)((u + 0x7fffu + ((u >> 16) & 1u)) >> 16);   // RNE
}

// ---------------------------------------------------------------------------
// Kernel A: per-block LDS histogram (packed 2x16b counters, CU-local atomics)
// + edge local ranks. Last block instead converts the weight matrices to bf16.
// ---------------------------------------------------------------------------
__global__ __launch_bounds__(256, 1)
void count_hist(const int* __restrict__ ei, ushort_t* __restrict__ lrank,
                ushort_t* __restrict__ histG,
                const float* __restrict__ Wl1, const float* __restrict__ Wr1,
                const float* __restrict__ Wl2, const float* __restrict__ Wr2,
                ushort_t* __restrict__ wab1, ushort_t* __restrict__ wab2,
                int E, int n, int EPB)
{
    const int tid = threadIdx.x;
    const int b   = blockIdx.x;

    if (b == NBLK) {                               // ---- setup tail block ----
        for (int k = tid; k < 2 * 64 * 128; k += 256)
            wab1[k] = f2bf(k < 64 * 128 ? Wl1[k] : Wr1[k - 64 * 128]);
        for (int k = tid; k < 2 * 32 * 64; k += 256)
            wab2[k] = f2bf(k < 32 * 64 ? Wl2[k] : Wr2[k - 32 * 64]);
        return;
    }

    __shared__ unsigned h[MAXNH];                  // 100 KB
    const int nh = (n + 1) >> 1;
    for (int i = tid; i < nh; i += 256) h[i] = 0u;
    __syncthreads();

    const int e0 = b * EPB;
    const int e1 = min(e0 + EPB, E);
    for (int e = e0 + tid; e < e1; e += 256) {
        int d = ei[E + e];
        unsigned sh  = (unsigned)(d & 1) * 16u;
        unsigned old = atomicAdd(&h[d >> 1], 1u << sh);     // LDS atomic
        lrank[e] = (ushort_t)((old >> sh) & 0xffffu);
    }
    __syncthreads();

    ushort_t* row = histG + (size_t)b * n;         // coalesced row dump
    for (int i = tid; i < n; i += 256) {
        unsigned v = h[i >> 1];
        row[i] = (ushort_t)((v >> ((i & 1) * 16)) & 0xffffu);
    }
}

// ---------------------------------------------------------------------------
// Kernel B: fused [col_scan + scan_p1 | gemm1] — r5-proven.
// ---------------------------------------------------------------------------
template<int N, int K>
__global__ __launch_bounds__(256, 2)
void colscan_plus_gemm(ushort_t* __restrict__ histG, int* __restrict__ cnt,
                       int* __restrict__ bsums, int n, int csBlocks,
                       const float* __restrict__ X, const ushort_t* __restrict__ Wab,
                       const float* __restrict__ ba, const float* __restrict__ bb,
                       ushort_t* __restrict__ OutA, ushort_t* __restrict__ OutB,
                       int M)
{
    constexpr int KC = K / 32;
    constexpr int NT = N / 16;
    __shared__ ushort_t sW[N * K];
    __shared__ ushort_t sX[64 * K];
    __shared__ int s[256];
    const int tid = threadIdx.x;

    if (blockIdx.x < csBlocks) {                // ---- colscan + p1 path ----
        int idx = blockIdx.x * 256 + tid;
        unsigned acc = 0;
        if (idx < n) {
            #pragma unroll 1
            for (int b0 = 0; b0 < NBLK; b0 += 16) {
                ushort_t c[16];
                #pragma unroll
                for (int j = 0; j < 16; ++j)
                    c[j] = histG[(size_t)(b0 + j) * n + idx];
                #pragma unroll
                for (int j = 0; j < 16; ++j) {
                    unsigned cc = c[j];
                    histG[(size_t)(b0 + j) * n + idx] = (ushort_t)acc;
                    acc += cc;
                }
            }
            cnt[idx] = (int)acc;
        }
        s[tid] = (idx < n) ? (int)acc : 0;      // fused scan_p1 tile reduce
        __syncthreads();
        #pragma unroll
        for (int off = 128; off >= 1; off >>= 1) {
            if (tid < off) s[tid] += s[tid + off];
            __syncthreads();
        }
        if (tid == 0) bsums[blockIdx.x] = s[0];
        return;
    }

    // ---- gemm path ----
    const int m0 = (blockIdx.x - csBlocks) * 64;

    auto swz = [](int r, int e) {
        return r * K + ((((e >> 3) ^ (r & 7)) << 3) | (e & 7));
    };

    constexpr int WQ8 = N * K / 8;
    for (int q = tid; q < WQ8; q += 256) {
        int nrow = q / (K / 8);
        int e8   = (q % (K / 8)) * 8;
        uint4 v = *(const uint4*)(Wab + (size_t)nrow * K + e8);
        *(uint4*)&sW[swz(nrow, e8)] = v;
    }
    constexpr int XQ = 64 * (K / 4);
    for (int q = tid; q < XQ; q += 256) {
        int r  = q / (K / 4);
        int k4 = (q % (K / 4)) * 4;
        float4 v = make_float4(0.f, 0.f, 0.f, 0.f);
        int gr = m0 + r;
        if (gr < M) v = *(const float4*)(X + (size_t)gr * K + k4);
        short4 h = make_short4((short)f2bf(v.x), (short)f2bf(v.y),
                               (short)f2bf(v.z), (short)f2bf(v.w));
        *(short4*)&sX[swz(r, k4)] = h;
    }
    __syncthreads();

    const int wv   = tid >> 6;
    const int lane = tid & 63;
    const int mrow = lane & 15;
    const int quad = lane >> 4;

    bf16x8 a[KC];
    #pragma unroll
    for (int kc = 0; kc < KC; ++kc)
        a[kc] = *(const bf16x8*)&sX[swz(wv * 16 + mrow, kc * 32 + quad * 8)];

    #pragma unroll
    for (int nt = 0; nt < NT; ++nt) {
        f32x4 acc = {0.f, 0.f, 0.f, 0.f};
        #pragma unroll
        for (int kc = 0; kc < KC; ++kc) {
            bf16x8 bfr = *(const bf16x8*)&sW[swz(nt * 16 + mrow, kc * 32 + quad * 8)];
            acc = __builtin_amdgcn_mfma_f32_16x16x32_bf16(a[kc], bfr, acc, 0, 0, 0);
        }
        const int col = nt * 16 + mrow;
        ushort_t* dst;
        int cc;
        float bv;
        if (col < N / 2) { dst = OutA; cc = col;         bv = ba[cc]; }
        else             { dst = OutB; cc = col - N / 2; bv = bb[cc]; }
        #pragma unroll
        for (int r = 0; r < 4; ++r) {
            int row = m0 + wv * 16 + quad * 4 + r;
            if (row < M)
                dst[(size_t)row * (N / 2) + cc] = f2bf(acc[r] + bv);
        }
    }
}

// ---------------------------------------------------------------------------
// Kernel C: scan_p3 (unchanged, r13-proven) — row_off from cnt + bsums.
// ---------------------------------------------------------------------------
__global__ __launch_bounds__(256)
void scan_p3(const int* __restrict__ cnt, const int* __restrict__ bsums,
             int* __restrict__ row_off, int n, int nb)
{
    __shared__ int sb[256];
    __shared__ int s[256];
    const int tid = threadIdx.x;

    int bv = (tid < nb) ? bsums[tid] : 0;
    sb[tid] = bv;
    __syncthreads();
    #pragma unroll
    for (int off = 1; off < 256; off <<= 1) {       // inclusive scan of bsums
        int t = (tid >= off) ? sb[tid - off] : 0;
        __syncthreads();
        sb[tid] += t;
        __syncthreads();
    }
    int excl_t = sb[tid] - bv;                      // exclusive
    __syncthreads();
    sb[tid] = excl_t;
    __syncthreads();
    const int base = sb[blockIdx.x];

    int gi = blockIdx.x * 256 + tid;
    int c = (gi < n) ? cnt[gi] : 0;
    s[tid] = c;
    __syncthreads();
    #pragma unroll
    for (int off = 1; off < 256; off <<= 1) {       // inclusive scan of tile
        int t = (tid >= off) ? s[tid - off] : 0;
        __syncthreads();
        s[tid] += t;
        __syncthreads();
    }
    if (gi < n) {
        int excl = base + s[tid] - c;
        row_off[gi] = excl;
        if (gi == n - 1) row_off[n] = excl + c;     // == E
    }
}

// ---------------------------------------------------------------------------
// Kernel D: scatter with LDS-staged per-row base offsets — r5-proven.
// ---------------------------------------------------------------------------
__global__ __launch_bounds__(256, 1)
void scat_lds(const int* __restrict__ ei, const float* __restrict__ ew,
              const int* __restrict__ row_off, const ushort_t* __restrict__ lrank,
              const ushort_t* __restrict__ boff, int2* __restrict__ slot,
              int E, int n, int EPB)
{
    __shared__ ushort_t sb[2 * MAXNH];             // 100 KB (n <= 50048)
    const int tid = threadIdx.x;
    const int b   = blockIdx.x;

    const ushort_t* row = boff + (size_t)b * n;
    {
        if ((n & 1) == 0 && (((size_t)b * n) & 1) == 0) {
            const unsigned* r32 = (const unsigned*)row;
            unsigned* s32 = (unsigned*)sb;
            for (int i = tid; i < (n >> 1); i += 256) s32[i] = r32[i];
        } else {
            for (int i = tid; i < n; i += 256) sb[i] = row[i];
        }
    }
    __syncthreads();

    const int e0 = b * EPB;
    const int e1 = min(e0 + EPB, E);
    for (int base = e0 + tid; base < e1; base += 256 * 4) {
        int dd[4], ss[4];
        ushort_t rr[4];
        float ww[4];
        #pragma unroll
        for (int j = 0; j < 4; ++j) {              // batch loads 4 deep
            int e = base + j * 256;
            if (e < e1) {
                dd[j] = ei[E + e];
                rr[j] = lrank[e];
                ss[j] = ei[e];
                ww[j] = ew[e];
            }
        }
        #pragma unroll
        for (int j = 0; j < 4; ++j) {
            int e = base + j * 256;
            if (e < e1) {
                int pos = row_off[dd[j]] + (int)sb[dd[j]] + (int)rr[j];
                slot[pos] = make_int2(ss[j], __float_as_int(ww[j]));
            }
        }
    }
}

// ---------------------------------------------------------------------------
// MFMA fused linear (standalone, used for layer 2) — r13-proven.
// ---------------------------------------------------------------------------
template<int N, int K>
__global__ __launch_bounds__(256, 2)
void gemm_xw_mfma(const float* __restrict__ X, const ushort_t* __restrict__ Wab,
                  const float* __restrict__ ba, const float* __restrict__ bb,
                  ushort_t* __restrict__ OutA, ushort_t* __restrict__ OutB, int M)
{
    constexpr int KC = K / 32;
    constexpr int NT = N / 16;
    __shared__ ushort_t sW[N * K];
    __shared__ ushort_t sX[64 * K];
    const int tid = threadIdx.x;
    const int m0  = blockIdx.x * 64;

    auto swz = [](int r, int e) {
        return r * K + ((((e >> 3) ^ (r & 7)) << 3) | (e & 7));
    };

    constexpr int WQ8 = N * K / 8;
    for (int q = tid; q < WQ8; q += 256) {
        int nrow = q / (K / 8);
        int e8   = (q % (K / 8)) * 8;
        uint4 v = *(const uint4*)(Wab + (size_t)nrow * K + e8);
        *(uint4*)&sW[swz(nrow, e8)] = v;
    }
    constexpr int XQ = 64 * (K / 4);
    for (int q = tid; q < XQ; q += 256) {
        int r  = q / (K / 4);
        int k4 = (q % (K / 4)) * 4;
        float4 v = make_float4(0.f, 0.f, 0.f, 0.f);
        int gr = m0 + r;
        if (gr < M) v = *(const float4*)(X + (size_t)gr * K + k4);
        short4 h = make_short4((short)f2bf(v.x), (short)f2bf(v.y),
                               (short)f2bf(v.z), (short)f2bf(v.w));
        *(short4*)&sX[swz(r, k4)] = h;
    }
    __syncthreads();

    const int wv   = tid >> 6;
    const int lane = tid & 63;
    const int mrow = lane & 15;
    const int quad = lane >> 4;

    bf16x8 a[KC];
    #pragma unroll
    for (int kc = 0; kc < KC; ++kc)
        a[kc] = *(const bf16x8*)&sX[swz(wv * 16 + mrow, kc * 32 + quad * 8)];

    #pragma unroll
    for (int nt = 0; nt < NT; ++nt) {
        f32x4 acc = {0.f, 0.f, 0.f, 0.f};
        #pragma unroll
        for (int kc = 0; kc < KC; ++kc) {
            bf16x8 bfr = *(const bf16x8*)&sW[swz(nt * 16 + mrow, kc * 32 + quad * 8)];
            acc = __builtin_amdgcn_mfma_f32_16x16x32_bf16(a[kc], bfr, acc, 0, 0, 0);
        }
        const int col = nt * 16 + mrow;
        ushort_t* dst;
        int cc;
        float bv;
        if (col < N / 2) { dst = OutA; cc = col;         bv = ba[cc]; }
        else             { dst = OutB; cc = col - N / 2; bv = bb[cc]; }
        #pragma unroll
        for (int r = 0; r < 4; ++r) {
            int row = m0 + wv * 16 + quad * 4 + r;
            if (row < M)
                dst[(size_t)row * (N / 2) + cc] = f2bf(acc[r] + bv);
        }
    }
}

// ---------------------------------------------------------------------------
// Per-node GATv2 attention + aggregation — r6: 8 dims per lane (uint4 loads).
// LPE = D/8 lanes/edge, SG = 64/LPE edges per round (8 for D=64, 16 for
// D=32). 4-deep prefetch, tail + self-loop gathers hoisted into the entry
// prefetch. ACT: 0 = ELU, 1 = softplus + 1e-4.
// ---------------------------------------------------------------------------
template<int D, int ACT>
__global__ __launch_bounds__(256)
void edge_attn(const ushort_t* __restrict__ xl, const ushort_t* __restrict__ xr,
               const float* __restrict__ We, const float* __restrict__ att,
               const float* __restrict__ bias,
               const int* __restrict__ row_off, const int2* __restrict__ slot,
               float* __restrict__ out, int n)
{
    constexpr int LPE = D / 8;                 // lanes per edge (8 dims each)
    constexpr int SG  = 64 / LPE;              // edges per round
    const int lane = threadIdx.x & 63;
    const int wid  = threadIdx.x >> 6;
    const int t    = lane % LPE;               // owns dims 8t..8t+7
    const int g    = lane / LPE;               // edge slot within round
    const int node = blockIdx.x * 4 + wid;
    if (node >= n) return;

    auto unpack = [](unsigned lo, unsigned hi) -> float4 {
        float4 r;
        r.x = __uint_as_float(lo << 16);
        r.y = __uint_as_float(lo & 0xffff0000u);
        r.z = __uint_as_float(hi << 16);
        r.w = __uint_as_float(hi & 0xffff0000u);
        return r;
    };

    const float4 WeL = *(const float4*)(We  + 8 * t);
    const float4 WeH = *(const float4*)(We  + 8 * t + 4);
    const float4 atL = *(const float4*)(att + 8 * t);
    const float4 atH = *(const float4*)(att + 8 * t + 4);
    const float4 biL = *(const float4*)(bias + 8 * t);
    const float4 biH = *(const float4*)(bias + 8 * t + 4);
    const uint4  xru = *(const uint4*)(xr + (size_t)node * D + 8 * t);
    const float4 xrL = unpack(xru.x, xru.y);
    const float4 xrH = unpack(xru.z, xru.w);

    const int start = row_off[node];
    const int end   = row_off[node + 1];
    const int R  = (end - start) / SG;         // full rounds
    const int jt = start + R * SG;             // tail begin
    const bool has_tail = jt < end;

    // ---- entry prefetch: main pipeline + tail + self-loop all in flight ----
    int2  q[4];
    uint4 xv[4];
    #pragma unroll
    for (int s = 0; s < 4; ++s) {
        if (s < R) {
            q[s]  = slot[start + s * SG + g];
            xv[s] = *(const uint4*)(xl + (size_t)q[s].x * D + 8 * t);
        }
    }
    int2 tq = make_int2(0, 0);
    uint4 tx = make_uint4(0u, 0u, 0u, 0u);
    if (has_tail) {
        int idx = min(jt + g, end - 1);
        tq = slot[idx];
        tx = *(const uint4*)(xl + (size_t)tq.x * D + 8 * t);
    }
    const uint4 xs = *(const uint4*)(xl + (size_t)node * D + 8 * t); // self

    float denom = 0.f, wsum = 0.f;
    float4 accL = make_float4(0.f, 0.f, 0.f, 0.f);
    float4 accH = make_float4(0.f, 0.f, 0.f, 0.f);

    auto body = [&](int2 qe, uint4 cx, bool active) {
        float w = __int_as_float(qe.y);
        float4 xL = unpack(cx.x, cx.y);
        float4 xH = unpack(cx.z, cx.w);
        float4 vL, vH;
        vL.x = xL.x + fmaf(w, WeL.x, xrL.x);
        vL.y = xL.y + fmaf(w, WeL.y, xrL.y);
        vL.z = xL.z + fmaf(w, WeL.z, xrL.z);
        vL.w = xL.w + fmaf(w, WeL.w, xrL.w);
        vH.x = xH.x + fmaf(w, WeH.x, xrH.x);
        vH.y = xH.y + fmaf(w, WeH.y, xrH.y);
        vH.z = xH.z + fmaf(w, WeH.z, xrH.z);
        vH.w = xH.w + fmaf(w, WeH.w, xrH.w);
        float p;
        p  = atL.x * fmaxf(vL.x, 0.2f * vL.x);
        p  = fmaf(atL.y, fmaxf(vL.y, 0.2f * vL.y), p);
        p  = fmaf(atL.z, fmaxf(vL.z, 0.2f * vL.z), p);
        p  = fmaf(atL.w, fmaxf(vL.w, 0.2f * vL.w), p);
        p  = fmaf(atH.x, fmaxf(vH.x, 0.2f * vH.x), p);
        p  = fmaf(atH.y, fmaxf(vH.y, 0.2f * vH.y), p);
        p  = fmaf(atH.z, fmaxf(vH.z, 0.2f * vH.z), p);
        p  = fmaf(atH.w, fmaxf(vH.w, 0.2f * vH.w), p);
        p = group_reduce<LPE>(p);              // per-edge score, DPP only
        float e = active ? __expf(p) : 0.f;
        wsum  += active ? w : 0.f;
        denom += e;
        accL.x = fmaf(e, xL.x, accL.x);
        accL.y = fmaf(e, xL.y, accL.y);
        accL.z = fmaf(e, xL.z, accL.z);
        accL.w = fmaf(e, xL.w, accL.w);
        accH.x = fmaf(e, xH.x, accH.x);
        accH.y = fmaf(e, xH.y, accH.y);
        accH.z = fmaf(e, xH.z, accH.z);
        accH.w = fmaf(e, xH.w, accH.w);
    };

    int b = 0;
    for (; b + 4 <= R; b += 4) {               // steady state
        #pragma unroll
        for (int s = 0; s < 4; ++s) {
            int2 cq = q[s]; uint4 cx = xv[s];
            int nr = b + 4 + s;
            if (nr < R) {                      // refill stage s
                q[s]  = slot[start + nr * SG + g];
                xv[s] = *(const uint4*)(xl + (size_t)q[s].x * D + 8 * t);
            }
            body(cq, cx, true);
        }
    }
    #pragma unroll
    for (int s = 0; s < 4; ++s)                // leftover full rounds
        if (b + s < R) body(q[s], xv[s], true);

    if (has_tail)                              // tail round (data prefetched)
        body(tq, tx, (jt + g) < end);

    // combine partials across the SG subgroups (once per node)
    #pragma unroll
    for (int mask = LPE; mask < 64; mask <<= 1) {
        denom  += __shfl_xor(denom,  mask);
        wsum   += __shfl_xor(wsum,   mask);
        accL.x += __shfl_xor(accL.x, mask);
        accL.y += __shfl_xor(accL.y, mask);
        accL.z += __shfl_xor(accL.z, mask);
        accL.w += __shfl_xor(accL.w, mask);
        accH.x += __shfl_xor(accH.x, mask);
        accH.y += __shfl_xor(accH.y, mask);
        accH.z += __shfl_xor(accH.z, mask);
        accH.w += __shfl_xor(accH.w, mask);
    }

    {   // self-loop: w = mean of incoming edge weights (xs prefetched)
        float w = wsum / (float)max(end - start, 1);
        float4 xL = unpack(xs.x, xs.y);
        float4 xH = unpack(xs.z, xs.w);
        float4 vL, vH;
        vL.x = xL.x + fmaf(w, WeL.x, xrL.x);
        vL.y = xL.y + fmaf(w, WeL.y, xrL.y);
        vL.z = xL.z + fmaf(w, WeL.z, xrL.z);
        vL.w = xL.w + fmaf(w, WeL.w, xrL.w);
        vH.x = xH.x + fmaf(w, WeH.x, xrH.x);
        vH.y = xH.y + fmaf(w, WeH.y, xrH.y);
        vH.z = xH.z + fmaf(w, WeH.z, xrH.z);
        vH.w = xH.w + fmaf(w, WeH.w, xrH.w);
        float p;
        p  = atL.x * fmaxf(vL.x, 0.2f * vL.x);
        p  = fmaf(atL.y, fmaxf(vL.y, 0.2f * vL.y), p);
        p  = fmaf(atL.z, fmaxf(vL.z, 0.2f * vL.z), p);
        p  = fmaf(atL.w, fmaxf(vL.w, 0.2f * vL.w), p);
        p  = fmaf(atH.x, fmaxf(vH.x, 0.2f * vH.x), p);
        p  = fmaf(atH.y, fmaxf(vH.y, 0.2f * vH.y), p);
        p  = fmaf(atH.z, fmaxf(vH.z, 0.2f * vH.z), p);
        p  = fmaf(atH.w, fmaxf(vH.w, 0.2f * vH.w), p);
        p = group_reduce<LPE>(p);
        float e = __expf(p);
        denom += e;
        accL.x = fmaf(e, xL.x, accL.x);
        accL.y = fmaf(e, xL.y, accL.y);
        accL.z = fmaf(e, xL.z, accL.z);
        accL.w = fmaf(e, xL.w, accL.w);
        accH.x = fmaf(e, xH.x, accH.x);
        accH.y = fmaf(e, xH.y, accH.y);
        accH.z = fmaf(e, xH.z, accH.z);
        accH.w = fmaf(e, xH.w, accH.w);
    }

    float4 rL, rH;
    rL.x = accL.x / denom + biL.x;
    rL.y = accL.y / denom + biL.y;
    rL.z = accL.z / denom + biL.z;
    rL.w = accL.w / denom + biL.w;
    rH.x = accH.x / denom + biH.x;
    rH.y = accH.y / denom + biH.y;
    rH.z = accH.z / denom + biH.z;
    rH.w = accH.w / denom + biH.w;
    if (ACT == 0) {
        // ELU via hw exp: max(r,0) + exp(min(r,0)) - 1   (exact for r>=0)
        rL.x = fmaxf(rL.x, 0.f) + __expf(fminf(rL.x, 0.f)) - 1.f;
        rL.y = fmaxf(rL.y, 0.f) + __expf(fminf(rL.y, 0.f)) - 1.f;
        rL.z = fmaxf(rL.z, 0.f) + __expf(fminf(rL.z, 0.f)) - 1.f;
        rL.w = fmaxf(rL.w, 0.f) + __expf(fminf(rL.w, 0.f)) - 1.f;
        rH.x = fmaxf(rH.x, 0.f) + __expf(fminf(rH.x, 0.f)) - 1.f;
        rH.y = fmaxf(rH.y, 0.f) + __expf(fminf(rH.y, 0.f)) - 1.f;
        rH.z = fmaxf(rH.z, 0.f) + __expf(fminf(rH.z, 0.f)) - 1.f;
        rH.w = fmaxf(rH.w, 0.f) + __expf(fminf(rH.w, 0.f)) - 1.f;
    } else {
        // softplus via hw exp/log + 1e-4
        rL.x = fmaxf(rL.x, 0.f) + __logf(1.f + __expf(-fabsf(rL.x))) + 1e-4f;
        rL.y = fmaxf(rL.y, 0.f) + __logf(1.f + __expf(-fabsf(rL.y))) + 1e-4f;
        rL.z = fmaxf(rL.z, 0.f) + __logf(1.f + __expf(-fabsf(rL.z))) + 1e-4f;
        rL.w = fmaxf(rL.w, 0.f) + __logf(1.f + __expf(-fabsf(rL.w))) + 1e-4f;
        rH.x = fmaxf(rH.x, 0.f) + __logf(1.f + __expf(-fabsf(rH.x))) + 1e-4f;
        rH.y = fmaxf(rH.y, 0.f) + __logf(1.f + __expf(-fabsf(rH.y))) + 1e-4f;
        rH.z = fmaxf(rH.z, 0.f) + __logf(1.f + __expf(-fabsf(rH.z))) + 1e-4f;
        rH.w = fmaxf(rH.w, 0.f) + __logf(1.f + __expf(-fabsf(rH.w))) + 1e-4f;
    }
    if (g == 0) {
        *(float4*)(out + (size_t)node * D + 8 * t)     = rL;
        *(float4*)(out + (size_t)node * D + 8 * t + 4) = rH;
    }
}

// ---------------------------------------------------------------------------
extern "C" void kernel_launch(void* const* d_in, const int* in_sizes, int n_in,
                              void* d_out, int out_size, void* d_ws, size_t ws_size,
                              hipStream_t stream)
{
    const float* x     = (const float*)d_in[0];
    const int*   ei    = (const int*)d_in[1];     // (2, E) int32
    const float* ew    = (const float*)d_in[2];
    const float* Wl1   = (const float*)d_in[3];
    const float* bl1   = (const float*)d_in[4];
    const float* Wr1   = (const float*)d_in[5];
    const float* br1   = (const float*)d_in[6];
    const float* We1   = (const float*)d_in[7];
    const float* att1  = (const float*)d_in[8];
    const float* bias1 = (const float*)d_in[9];
    const float* Wl2   = (const float*)d_in[10];
    const float* bl2   = (const float*)d_in[11];
    const float* Wr2   = (const float*)d_in[12];
    const float* br2   = (const float*)d_in[13];
    const float* We2   = (const float*)d_in[14];
    const float* att2  = (const float*)d_in[15];
    const float* bias2 = (const float*)d_in[16];
    float* out = (float*)d_out;

    const int n = in_sizes[0] / 128;
    const int E = in_sizes[2];
    const int NB = (n + 255) / 256;               // 196 (<= 256 required)
    const int EPB = (E + NBLK - 1) / NBLK;        // edges per histogram block
    const int gemmBlocks = (n + 63) / 64;

    char* wp = (char*)d_ws;
    auto carve = [&](size_t bytes) -> void* {
        void* p = (void*)wp;
        wp += (bytes + 255) & ~(size_t)255;
        return p;
    };
    int*      cnt     = (int*)     carve((size_t)n * 4);
    int*      row_off = (int*)     carve((size_t)(n + 1) * 4);
    ushort_t* lrank   = (ushort_t*)carve((size_t)E * 2);
    ushort_t* histG   = (ushort_t*)carve((size_t)NBLK * n * 2);   // -> boff
    int*      bsums   = (int*)     carve((size_t)256 * 4);
    int2*     slot    = (int2*)    carve((size_t)E * 8);
    ushort_t* wab1    = (ushort_t*)carve((size_t)2 * 64 * 128 * 2);
    ushort_t* wab2    = (ushort_t*)carve((size_t)2 * 32 * 64 * 2);
    ushort_t* xl1     = (ushort_t*)carve((size_t)n * 64 * 2);
    ushort_t* xr1     = (ushort_t*)carve((size_t)n * 64 * 2);
    float*    hbuf    = (float*)   carve((size_t)n * 64 * 4);
    ushort_t* xl2     = (ushort_t*)carve((size_t)n * 32 * 2);
    ushort_t* xr2     = (ushort_t*)carve((size_t)n * 32 * 2);

    // A: histograms + local ranks (+ weight conversion in tail block)
    count_hist<<<NBLK + 1, 256, 0, stream>>>(ei, lrank, histG,
                                             Wl1, Wr1, Wl2, Wr2, wab1, wab2,
                                             E, n, EPB);
    // B: [col_scan + scan_p1] || layer-1 GEMM
    colscan_plus_gemm<128, 128><<<NB + gemmBlocks, 256, 0, stream>>>(
        histG, cnt, bsums, n, NB, x, wab1, bl1, br1, xl1, xr1, n);
    // C: row_off
    scan_p3<<<NB, 256, 0, stream>>>(cnt, bsums, row_off, n, NB);
    // D: scatter with LDS-staged per-row base offsets
    scat_lds<<<NBLK, 256, 0, stream>>>(ei, ew, row_off, lrank, histG, slot,
                                       E, n, EPB);

    edge_attn<64, 0><<<(n + 3) / 4, 256, 0, stream>>>(xl1, xr1, We1, att1, bias1,
                                                      row_off, slot, hbuf, n);
    gemm_xw_mfma<64, 64><<<(n + 63) / 64, 256, 0, stream>>>(hbuf, wab2, bl2, br2,
                                                            xl2, xr2, n);
    edge_attn<32, 1><<<(n + 3) / 4, 256, 0, stream>>>(xl2, xr2, We2, att2, bias2,
                                                      row_off, slot, out, n);
}

// Round 7
// 238.720 us; speedup vs baseline: 1.1198x; 1.1198x over previous
//
#include <hip/hip_runtime.h>
#include <math.h>

typedef unsigned short ushort_t;
typedef __attribute__((ext_vector_type(8))) short bf16x8;   // MFMA A/B frag (4 VGPR)
typedef __attribute__((ext_vector_type(4))) float f32x4;    // MFMA C/D frag

// r6 post-mortem: uint4 edge_attn REGRESSED (43.4->54.4us: VGPR 40->64,
// occ 48->36%, tail waste doubled, combine 12->30 shfl). Reverted to the
// r5 uint2 version. r7 structural fix: count_hist/scat_lds ran 128 blocks
// x 100KB LDS = 1 block/CU = HALF the device idle. Split each edge-slice's
// work into 2 blocks owning half the node range (50KB LDS each, 256 blocks,
// 2-3 blocks/CU). dst re-read by both halves (+3.2MB); src/ew/lrank loads
// predicated to the owning half. histG layout unchanged.
#define NBLK  128         // histogram edge slices (EPB = E/NBLK edges each)
#define HNH   12512       // LDS uints, packed 2x16b counters, half node range
#define HNS   25024       // LDS ushorts, staged boff row, half node range

// ---------------------------------------------------------------------------
// DPP-based add: x += x[lane ^ pattern], pure VALU.
// ---------------------------------------------------------------------------
template<int CTRL>
__device__ __forceinline__ float dpp_addf(float x)
{
    int y = __builtin_amdgcn_update_dpp(0, __float_as_int(x), CTRL, 0xf, 0xf, true);
    return x + __int_as_float(y);
}

template<int LPE>
__device__ __forceinline__ float group_reduce(float p)
{
    p = dpp_addf<0xB1>(p);                           // xor 1
    p = dpp_addf<0x4E>(p);                           // xor 2
    if constexpr (LPE >= 8)  p = dpp_addf<0x141>(p); // xor 7 (row_half_mirror)
    if constexpr (LPE >= 16) p = dpp_addf<0x140>(p); // xor 15 (row_mirror)
    return p;
}

__device__ __forceinline__ ushort_t f2bf(float f)
{
    unsigned u = __float_as_uint(f);
    return (ushort_t)((u + 0x7fffu + ((u >> 16) & 1u)) >> 16);   // RNE
}

// ---------------------------------------------------------------------------
// Kernel A: per-(slice,half) LDS histogram. Block bb: slice b = bb>>1,
// node-half = bb&1 (range [h0,h1)). Packed 2x16b counters in 50KB LDS.
// Edge dst read by both halves; only the owner counts + writes lrank.
// Last block (bb == 2*NBLK) converts the weight matrices to bf16.
// ---------------------------------------------------------------------------
__global__ __launch_bounds__(256, 2)
void count_hist(const int* __restrict__ ei, ushort_t* __restrict__ lrank,
                ushort_t* __restrict__ histG,
                const float* __restrict__ Wl1, const float* __restrict__ Wr1,
                const float* __restrict__ Wl2, const float* __restrict__ Wr2,
                ushort_t* __restrict__ wab1, ushort_t* __restrict__ wab2,
                int E, int n, int EPB)
{
    const int tid = threadIdx.x;
    const int bb  = blockIdx.x;

    if (bb == 2 * NBLK) {                          // ---- setup tail block ----
        for (int k = tid; k < 2 * 64 * 128; k += 256)
            wab1[k] = f2bf(k < 64 * 128 ? Wl1[k] : Wr1[k - 64 * 128]);
        for (int k = tid; k < 2 * 32 * 64; k += 256)
            wab2[k] = f2bf(k < 32 * 64 ? Wl2[k] : Wr2[k - 32 * 64]);
        return;
    }

    const int b    = bb >> 1;
    const int half = bb & 1;
    const int H    = (n + 1) >> 1;
    const int h0   = half * H;
    const int span = min(h0 + H, n) - h0;

    __shared__ unsigned h[HNH];                    // 50 KB
    const int nh = (span + 1) >> 1;
    for (int i = tid; i < nh; i += 256) h[i] = 0u;
    __syncthreads();

    const int e0 = b * EPB;
    const int e1 = min(e0 + EPB, E);
    for (int e = e0 + tid; e < e1; e += 256) {
        int d = ei[E + e];
        unsigned li = (unsigned)(d - h0);
        if (li < (unsigned)span) {
            unsigned sh  = (li & 1) * 16u;
            unsigned old = atomicAdd(&h[li >> 1], 1u << sh);   // LDS atomic
            lrank[e] = (ushort_t)((old >> sh) & 0xffffu);
        }
    }
    __syncthreads();

    ushort_t* row = histG + (size_t)b * n + h0;    // coalesced half-row dump
    for (int i = tid; i < span; i += 256) {
        unsigned v = h[i >> 1];
        row[i] = (ushort_t)((v >> ((i & 1) * 16)) & 0xffffu);
    }
}

// ---------------------------------------------------------------------------
// Kernel B: fused [col_scan + scan_p1 | gemm1] — r5-proven.
// ---------------------------------------------------------------------------
template<int N, int K>
__global__ __launch_bounds__(256, 2)
void colscan_plus_gemm(ushort_t* __restrict__ histG, int* __restrict__ cnt,
                       int* __restrict__ bsums, int n, int csBlocks,
                       const float* __restrict__ X, const ushort_t* __restrict__ Wab,
                       const float* __restrict__ ba, const float* __restrict__ bb,
                       ushort_t* __restrict__ OutA, ushort_t* __restrict__ OutB,
                       int M)
{
    constexpr int KC = K / 32;
    constexpr int NT = N / 16;
    __shared__ ushort_t sW[N * K];
    __shared__ ushort_t sX[64 * K];
    __shared__ int s[256];
    const int tid = threadIdx.x;

    if (blockIdx.x < csBlocks) {                // ---- colscan + p1 path ----
        int idx = blockIdx.x * 256 + tid;
        unsigned acc = 0;
        if (idx < n) {
            #pragma unroll 1
            for (int b0 = 0; b0 < NBLK; b0 += 16) {
                ushort_t c[16];
                #pragma unroll
                for (int j = 0; j < 16; ++j)
                    c[j] = histG[(size_t)(b0 + j) * n + idx];
                #pragma unroll
                for (int j = 0; j < 16; ++j) {
                    unsigned cc = c[j];
                    histG[(size_t)(b0 + j) * n + idx] = (ushort_t)acc;
                    acc += cc;
                }
            }
            cnt[idx] = (int)acc;
        }
        s[tid] = (idx < n) ? (int)acc : 0;      // fused scan_p1 tile reduce
        __syncthreads();
        #pragma unroll
        for (int off = 128; off >= 1; off >>= 1) {
            if (tid < off) s[tid] += s[tid + off];
            __syncthreads();
        }
        if (tid == 0) bsums[blockIdx.x] = s[0];
        return;
    }

    // ---- gemm path ----
    const int m0 = (blockIdx.x - csBlocks) * 64;

    auto swz = [](int r, int e) {
        return r * K + ((((e >> 3) ^ (r & 7)) << 3) | (e & 7));
    };

    constexpr int WQ8 = N * K / 8;
    for (int q = tid; q < WQ8; q += 256) {
        int nrow = q / (K / 8);
        int e8   = (q % (K / 8)) * 8;
        uint4 v = *(const uint4*)(Wab + (size_t)nrow * K + e8);
        *(uint4*)&sW[swz(nrow, e8)] = v;
    }
    constexpr int XQ = 64 * (K / 4);
    for (int q = tid; q < XQ; q += 256) {
        int r  = q / (K / 4);
        int k4 = (q % (K / 4)) * 4;
        float4 v = make_float4(0.f, 0.f, 0.f, 0.f);
        int gr = m0 + r;
        if (gr < M) v = *(const float4*)(X + (size_t)gr * K + k4);
        short4 h = make_short4((short)f2bf(v.x), (short)f2bf(v.y),
                               (short)f2bf(v.z), (short)f2bf(v.w));
        *(short4*)&sX[swz(r, k4)] = h;
    }
    __syncthreads();

    const int wv   = tid >> 6;
    const int lane = tid & 63;
    const int mrow = lane & 15;
    const int quad = lane >> 4;

    bf16x8 a[KC];
    #pragma unroll
    for (int kc = 0; kc < KC; ++kc)
        a[kc] = *(const bf16x8*)&sX[swz(wv * 16 + mrow, kc * 32 + quad * 8)];

    #pragma unroll
    for (int nt = 0; nt < NT; ++nt) {
        f32x4 acc = {0.f, 0.f, 0.f, 0.f};
        #pragma unroll
        for (int kc = 0; kc < KC; ++kc) {
            bf16x8 bfr = *(const bf16x8*)&sW[swz(nt * 16 + mrow, kc * 32 + quad * 8)];
            acc = __builtin_amdgcn_mfma_f32_16x16x32_bf16(a[kc], bfr, acc, 0, 0, 0);
        }
        const int col = nt * 16 + mrow;
        ushort_t* dst;
        int cc;
        float bv;
        if (col < N / 2) { dst = OutA; cc = col;         bv = ba[cc]; }
        else             { dst = OutB; cc = col - N / 2; bv = bb[cc]; }
        #pragma unroll
        for (int r = 0; r < 4; ++r) {
            int row = m0 + wv * 16 + quad * 4 + r;
            if (row < M)
                dst[(size_t)row * (N / 2) + cc] = f2bf(acc[r] + bv);
        }
    }
}

// ---------------------------------------------------------------------------
// Kernel C: scan_p3 (unchanged, r13-proven) — row_off from cnt + bsums.
// ---------------------------------------------------------------------------
__global__ __launch_bounds__(256)
void scan_p3(const int* __restrict__ cnt, const int* __restrict__ bsums,
             int* __restrict__ row_off, int n, int nb)
{
    __shared__ int sb[256];
    __shared__ int s[256];
    const int tid = threadIdx.x;

    int bv = (tid < nb) ? bsums[tid] : 0;
    sb[tid] = bv;
    __syncthreads();
    #pragma unroll
    for (int off = 1; off < 256; off <<= 1) {       // inclusive scan of bsums
        int t = (tid >= off) ? sb[tid - off] : 0;
        __syncthreads();
        sb[tid] += t;
        __syncthreads();
    }
    int excl_t = sb[tid] - bv;                      // exclusive
    __syncthreads();
    sb[tid] = excl_t;
    __syncthreads();
    const int base = sb[blockIdx.x];

    int gi = blockIdx.x * 256 + tid;
    int c = (gi < n) ? cnt[gi] : 0;
    s[tid] = c;
    __syncthreads();
    #pragma unroll
    for (int off = 1; off < 256; off <<= 1) {       // inclusive scan of tile
        int t = (tid >= off) ? s[tid - off] : 0;
        __syncthreads();
        s[tid] += t;
        __syncthreads();
    }
    if (gi < n) {
        int excl = base + s[tid] - c;
        row_off[gi] = excl;
        if (gi == n - 1) row_off[n] = excl + c;     // == E
    }
}

// ---------------------------------------------------------------------------
// Kernel D: scatter, split like count_hist. Block bb: slice b = bb>>1,
// node-half = bb&1. Stages its 50KB half of boff row b into LDS; edges with
// dst outside the half are skipped (their pair block handles them).
// pos = row_off[d] (L2) + sb[d-h0] (LDS) + lrank[e]. No atomics.
// ---------------------------------------------------------------------------
__global__ __launch_bounds__(256, 2)
void scat_lds(const int* __restrict__ ei, const float* __restrict__ ew,
              const int* __restrict__ row_off, const ushort_t* __restrict__ lrank,
              const ushort_t* __restrict__ boff, int2* __restrict__ slot,
              int E, int n, int EPB)
{
    __shared__ ushort_t sb[HNS];                   // 50 KB
    const int tid  = threadIdx.x;
    const int bb   = blockIdx.x;
    const int b    = bb >> 1;
    const int half = bb & 1;
    const int H    = (n + 1) >> 1;
    const int h0   = half * H;
    const int span = min(h0 + H, n) - h0;

    const ushort_t* row = boff + (size_t)b * n + h0;
    if (((((size_t)b * n + h0) & 1) == 0) && ((span & 1) == 0)) {
        const unsigned* r32 = (const unsigned*)row;     // dword-coalesced
        unsigned* s32 = (unsigned*)sb;
        for (int i = tid; i < (span >> 1); i += 256) s32[i] = r32[i];
    } else {
        for (int i = tid; i < span; i += 256) sb[i] = row[i];
    }
    __syncthreads();

    const int e0 = b * EPB;
    const int e1 = min(e0 + EPB, E);
    for (int base = e0 + tid; base < e1; base += 256 * 4) {
        int dd[4];
        bool act[4];
        #pragma unroll
        for (int j = 0; j < 4; ++j) {              // dst first (both halves)
            int e = base + j * 256;
            dd[j]  = (e < e1) ? ei[E + e] : 0;
            act[j] = (e < e1) && ((unsigned)(dd[j] - h0) < (unsigned)span);
        }
        int ss[4];
        ushort_t rr[4];
        float ww[4];
        #pragma unroll
        for (int j = 0; j < 4; ++j) {              // predicated owner loads
            int e = base + j * 256;
            if (act[j]) {
                rr[j] = lrank[e];
                ss[j] = ei[e];
                ww[j] = ew[e];
            }
        }
        #pragma unroll
        for (int j = 0; j < 4; ++j) {
            if (act[j]) {
                int pos = row_off[dd[j]] + (int)sb[dd[j] - h0] + (int)rr[j];
                slot[pos] = make_int2(ss[j], __float_as_int(ww[j]));
            }
        }
    }
}

// ---------------------------------------------------------------------------
// MFMA fused linear (standalone, used for layer 2) — r13-proven.
// ---------------------------------------------------------------------------
template<int N, int K>
__global__ __launch_bounds__(256, 2)
void gemm_xw_mfma(const float* __restrict__ X, const ushort_t* __restrict__ Wab,
                  const float* __restrict__ ba, const float* __restrict__ bb,
                  ushort_t* __restrict__ OutA, ushort_t* __restrict__ OutB, int M)
{
    constexpr int KC = K / 32;
    constexpr int NT = N / 16;
    __shared__ ushort_t sW[N * K];
    __shared__ ushort_t sX[64 * K];
    const int tid = threadIdx.x;
    const int m0  = blockIdx.x * 64;

    auto swz = [](int r, int e) {
        return r * K + ((((e >> 3) ^ (r & 7)) << 3) | (e & 7));
    };

    constexpr int WQ8 = N * K / 8;
    for (int q = tid; q < WQ8; q += 256) {
        int nrow = q / (K / 8);
        int e8   = (q % (K / 8)) * 8;
        uint4 v = *(const uint4*)(Wab + (size_t)nrow * K + e8);
        *(uint4*)&sW[swz(nrow, e8)] = v;
    }
    constexpr int XQ = 64 * (K / 4);
    for (int q = tid; q < XQ; q += 256) {
        int r  = q / (K / 4);
        int k4 = (q % (K / 4)) * 4;
        float4 v = make_float4(0.f, 0.f, 0.f, 0.f);
        int gr = m0 + r;
        if (gr < M) v = *(const float4*)(X + (size_t)gr * K + k4);
        short4 h = make_short4((short)f2bf(v.x), (short)f2bf(v.y),
                               (short)f2bf(v.z), (short)f2bf(v.w));
        *(short4*)&sX[swz(r, k4)] = h;
    }
    __syncthreads();

    const int wv   = tid >> 6;
    const int lane = tid & 63;
    const int mrow = lane & 15;
    const int quad = lane >> 4;

    bf16x8 a[KC];
    #pragma unroll
    for (int kc = 0; kc < KC; ++kc)
        a[kc] = *(const bf16x8*)&sX[swz(wv * 16 + mrow, kc * 32 + quad * 8)];

    #pragma unroll
    for (int nt = 0; nt < NT; ++nt) {
        f32x4 acc = {0.f, 0.f, 0.f, 0.f};
        #pragma unroll
        for (int kc = 0; kc < KC; ++kc) {
            bf16x8 bfr = *(const bf16x8*)&sW[swz(nt * 16 + mrow, kc * 32 + quad * 8)];
            acc = __builtin_amdgcn_mfma_f32_16x16x32_bf16(a[kc], bfr, acc, 0, 0, 0);
        }
        const int col = nt * 16 + mrow;
        ushort_t* dst;
        int cc;
        float bv;
        if (col < N / 2) { dst = OutA; cc = col;         bv = ba[cc]; }
        else             { dst = OutB; cc = col - N / 2; bv = bb[cc]; }
        #pragma unroll
        for (int r = 0; r < 4; ++r) {
            int row = m0 + wv * 16 + quad * 4 + r;
            if (row < M)
                dst[(size_t)row * (N / 2) + cc] = f2bf(acc[r] + bv);
        }
    }
}

// ---------------------------------------------------------------------------
// Per-node GATv2 attention + aggregation — r5-proven version (reverted from
// r6's uint4 regression). bf16 xl/xr, LPE=D/4 lanes/edge, 4-deep prefetch,
// tail + self-loop gathers hoisted. ACT: 0 = ELU, 1 = softplus + 1e-4.
// ---------------------------------------------------------------------------
template<int D, int ACT>
__global__ __launch_bounds__(256)
void edge_attn(const ushort_t* __restrict__ xl, const ushort_t* __restrict__ xr,
               const float* __restrict__ We, const float* __restrict__ att,
               const float* __restrict__ bias,
               const int* __restrict__ row_off, const int2* __restrict__ slot,
               float* __restrict__ out, int n)
{
    constexpr int LPE = D / 4;                 // lanes per edge
    constexpr int SG  = 64 / LPE;              // edges per round
    const int lane = threadIdx.x & 63;
    const int wid  = threadIdx.x >> 6;
    const int t    = lane % LPE;               // owns dims 4t..4t+3
    const int g    = lane / LPE;               // edge slot within round
    const int node = blockIdx.x * 4 + wid;
    if (node >= n) return;

    auto unpack = [](uint2 d) -> float4 {
        float4 r;
        r.x = __uint_as_float(d.x << 16);
        r.y = __uint_as_float(d.x & 0xffff0000u);
        r.z = __uint_as_float(d.y << 16);
        r.w = __uint_as_float(d.y & 0xffff0000u);
        return r;
    };

    const float4 We4   = *(const float4*)(We   + 4 * t);
    const float4 att4  = *(const float4*)(att  + 4 * t);
    const float4 bias4 = *(const float4*)(bias + 4 * t);
    const float4 xr4   = unpack(*(const uint2*)(xr + (size_t)node * D + 4 * t));

    const int start = row_off[node];
    const int end   = row_off[node + 1];
    const int R  = (end - start) / SG;         // full rounds
    const int jt = start + R * SG;             // tail begin
    const bool has_tail = jt < end;

    // ---- entry prefetch: main pipeline + tail + self-loop all in flight ----
    int2  q[4];
    uint2 xv[4];
    #pragma unroll
    for (int s = 0; s < 4; ++s) {
        if (s < R) {
            q[s]  = slot[start + s * SG + g];
            xv[s] = *(const uint2*)(xl + (size_t)q[s].x * D + 4 * t);
        }
    }
    int2 tq = make_int2(0, 0);
    uint2 tx = make_uint2(0u, 0u);
    if (has_tail) {
        int idx = min(jt + g, end - 1);
        tq = slot[idx];
        tx = *(const uint2*)(xl + (size_t)tq.x * D + 4 * t);
    }
    const uint2 xs = *(const uint2*)(xl + (size_t)node * D + 4 * t); // self

    float denom = 0.f, wsum = 0.f;
    float4 acc = make_float4(0.f, 0.f, 0.f, 0.f);

    auto body = [&](int2 qe, float4 xvv, bool active) {
        float w = __int_as_float(qe.y);
        float4 v;
        v.x = xvv.x + fmaf(w, We4.x, xr4.x);
        v.y = xvv.y + fmaf(w, We4.y, xr4.y);
        v.z = xvv.z + fmaf(w, We4.z, xr4.z);
        v.w = xvv.w + fmaf(w, We4.w, xr4.w);
        float4 m;
        m.x = fmaxf(v.x, 0.2f * v.x);
        m.y = fmaxf(v.y, 0.2f * v.y);
        m.z = fmaxf(v.z, 0.2f * v.z);
        m.w = fmaxf(v.w, 0.2f * v.w);
        float p = att4.x * m.x + att4.y * m.y + att4.z * m.z + att4.w * m.w;
        p = group_reduce<LPE>(p);              // per-edge score, DPP only
        float e = active ? __expf(p) : 0.f;
        wsum  += active ? w : 0.f;
        denom += e;
        acc.x = fmaf(e, xvv.x, acc.x);
        acc.y = fmaf(e, xvv.y, acc.y);
        acc.z = fmaf(e, xvv.z, acc.z);
        acc.w = fmaf(e, xvv.w, acc.w);
    };

    int b = 0;
    for (; b + 4 <= R; b += 4) {               // steady state
        #pragma unroll
        for (int s = 0; s < 4; ++s) {
            int2 cq = q[s]; uint2 cx = xv[s];
            int nr = b + 4 + s;
            if (nr < R) {                      // refill stage s
                q[s]  = slot[start + nr * SG + g];
                xv[s] = *(const uint2*)(xl + (size_t)q[s].x * D + 4 * t);
            }
            body(cq, unpack(cx), true);
        }
    }
    #pragma unroll
    for (int s = 0; s < 4; ++s)                // leftover full rounds
        if (b + s < R) body(q[s], unpack(xv[s]), true);

    if (has_tail)                              // tail round (data prefetched)
        body(tq, unpack(tx), (jt + g) < end);

    // combine partials across the SG subgroups (once per node)
    #pragma unroll
    for (int mask = LPE; mask < 64; mask <<= 1) {
        denom += __shfl_xor(denom, mask);
        wsum  += __shfl_xor(wsum,  mask);
        acc.x += __shfl_xor(acc.x, mask);
        acc.y += __shfl_xor(acc.y, mask);
        acc.z += __shfl_xor(acc.z, mask);
        acc.w += __shfl_xor(acc.w, mask);
    }

    {   // self-loop: w = mean of incoming edge weights (xs prefetched)
        float w = wsum / (float)max(end - start, 1);
        float4 xvs = unpack(xs);
        float4 v;
        v.x = xvs.x + fmaf(w, We4.x, xr4.x);
        v.y = xvs.y + fmaf(w, We4.y, xr4.y);
        v.z = xvs.z + fmaf(w, We4.z, xr4.z);
        v.w = xvs.w + fmaf(w, We4.w, xr4.w);
        float4 m;
        m.x = fmaxf(v.x, 0.2f * v.x);
        m.y = fmaxf(v.y, 0.2f * v.y);
        m.z = fmaxf(v.z, 0.2f * v.z);
        m.w = fmaxf(v.w, 0.2f * v.w);
        float p = att4.x * m.x + att4.y * m.y + att4.z * m.z + att4.w * m.w;
        p = group_reduce<LPE>(p);
        float e = __expf(p);
        denom += e;
        acc.x = fmaf(e, xvs.x, acc.x);
        acc.y = fmaf(e, xvs.y, acc.y);
        acc.z = fmaf(e, xvs.z, acc.z);
        acc.w = fmaf(e, xvs.w, acc.w);
    }

    float4 res;
    res.x = acc.x / denom + bias4.x;
    res.y = acc.y / denom + bias4.y;
    res.z = acc.z / denom + bias4.z;
    res.w = acc.w / denom + bias4.w;
    if (ACT == 0) {
        // ELU via hw exp: max(r,0) + exp(min(r,0)) - 1   (exact for r>=0)
        res.x = fmaxf(res.x, 0.f) + __expf(fminf(res.x, 0.f)) - 1.f;
        res.y = fmaxf(res.y, 0.f) + __expf(fminf(res.y, 0.f)) - 1.f;
        res.z = fmaxf(res.z, 0.f) + __expf(fminf(res.z, 0.f)) - 1.f;
        res.w = fmaxf(res.w, 0.f) + __expf(fminf(res.w, 0.f)) - 1.f;
    } else {
        // softplus via hw exp/log + 1e-4
        res.x = fmaxf(res.x, 0.f) + __logf(1.f + __expf(-fabsf(res.x))) + 1e-4f;
        res.y = fmaxf(res.y, 0.f) + __logf(1.f + __expf(-fabsf(res.y))) + 1e-4f;
        res.z = fmaxf(res.z, 0.f) + __logf(1.f + __expf(-fabsf(res.z))) + 1e-4f;
        res.w = fmaxf(res.w, 0.f) + __logf(1.f + __expf(-fabsf(res.w))) + 1e-4f;
    }
    if (g == 0)
        *(float4*)(out + (size_t)node * D + 4 * t) = res;
}

// ---------------------------------------------------------------------------
extern "C" void kernel_launch(void* const* d_in, const int* in_sizes, int n_in,
                              void* d_out, int out_size, void* d_ws, size_t ws_size,
                              hipStream_t stream)
{
    const float* x     = (const float*)d_in[0];
    const int*   ei    = (const int*)d_in[1];     // (2, E) int32
    const float* ew    = (const float*)d_in[2];
    const float* Wl1   = (const float*)d_in[3];
    const float* bl1   = (const float*)d_in[4];
    const float* Wr1   = (const float*)d_in[5];
    const float* br1   = (const float*)d_in[6];
    const float* We1   = (const float*)d_in[7];
    const float* att1  = (const float*)d_in[8];
    const float* bias1 = (const float*)d_in[9];
    const float* Wl2   = (const float*)d_in[10];
    const float* bl2   = (const float*)d_in[11];
    const float* Wr2   = (const float*)d_in[12];
    const float* br2   = (const float*)d_in[13];
    const float* We2   = (const float*)d_in[14];
    const float* att2  = (const float*)d_in[15];
    const float* bias2 = (const float*)d_in[16];
    float* out = (float*)d_out;

    const int n = in_sizes[0] / 128;
    const int E = in_sizes[2];
    const int NB = (n + 255) / 256;               // 196 (<= 256 required)
    const int EPB = (E + NBLK - 1) / NBLK;        // edges per histogram slice
    const int gemmBlocks = (n + 63) / 64;

    char* wp = (char*)d_ws;
    auto carve = [&](size_t bytes) -> void* {
        void* p = (void*)wp;
        wp += (bytes + 255) & ~(size_t)255;
        return p;
    };
    int*      cnt     = (int*)     carve((size_t)n * 4);
    int*      row_off = (int*)     carve((size_t)(n + 1) * 4);
    ushort_t* lrank   = (ushort_t*)carve((size_t)E * 2);
    ushort_t* histG   = (ushort_t*)carve((size_t)NBLK * n * 2);   // -> boff
    int*      bsums   = (int*)     carve((size_t)256 * 4);
    int2*     slot    = (int2*)    carve((size_t)E * 8);
    ushort_t* wab1    = (ushort_t*)carve((size_t)2 * 64 * 128 * 2);
    ushort_t* wab2    = (ushort_t*)carve((size_t)2 * 32 * 64 * 2);
    ushort_t* xl1     = (ushort_t*)carve((size_t)n * 64 * 2);
    ushort_t* xr1     = (ushort_t*)carve((size_t)n * 64 * 2);
    float*    hbuf    = (float*)   carve((size_t)n * 64 * 4);
    ushort_t* xl2     = (ushort_t*)carve((size_t)n * 32 * 2);
    ushort_t* xr2     = (ushort_t*)carve((size_t)n * 32 * 2);

    // A: histograms + local ranks, 2 node-halves per slice (+ setup tail)
    count_hist<<<2 * NBLK + 1, 256, 0, stream>>>(ei, lrank, histG,
                                                 Wl1, Wr1, Wl2, Wr2, wab1, wab2,
                                                 E, n, EPB);
    // B: [col_scan + scan_p1] || layer-1 GEMM
    colscan_plus_gemm<128, 128><<<NB + gemmBlocks, 256, 0, stream>>>(
        histG, cnt, bsums, n, NB, x, wab1, bl1, br1, xl1, xr1, n);
    // C: row_off
    scan_p3<<<NB, 256, 0, stream>>>(cnt, bsums, row_off, n, NB);
    // D: scatter, 2 node-halves per slice
    scat_lds<<<2 * NBLK, 256, 0, stream>>>(ei, ew, row_off, lrank, histG, slot,
                                           E, n, EPB);

    edge_attn<64, 0><<<(n + 3) / 4, 256, 0, stream>>>(xl1, xr1, We1, att1, bias1,
                                                      row_off, slot, hbuf, n);
    gemm_xw_mfma<64, 64><<<(n + 63) / 64, 256, 0, stream>>>(hbuf, wab2, bl2, br2,
                                                            xl2, xr2, n);
    edge_attn<32, 1><<<(n + 3) / 4, 256, 0, stream>>>(xl2, xr2, We2, att2, bias2,
                                                      row_off, slot, out, n);
}